// Round 1
// baseline (158.442 us; speedup 1.0000x reference)
//
#include <hip/hip_runtime.h>
#include <hip/hip_bf16.h>

// Problem constants: B=32, S=127, new_seq=128, D=768, H=12, HD=64
#define NB 32
#define NS 128     // new_seq
#define SD 127     // S
#define ND 768
#define NH 12
#define HD 64

__device__ inline float waveReduceSum(float v){
  #pragma unroll
  for (int off=32; off>0; off>>=1) v += __shfl_xor(v, off);
  return v;
}
__device__ inline float waveReduceMax(float v){
  #pragma unroll
  for (int off=32; off>0; off>>=1) v = fmaxf(v, __shfl_xor(v, off));
  return v;
}

// Fold Wk into uk[h][c] = sum_d Wk[h*64+d, c] * wk_a[d]; bkdot[h] = bk_h . wk_a
__global__ void fold_k(const float* __restrict__ Wk, const float* __restrict__ bk,
                       const float* __restrict__ Wa, float* __restrict__ uk,
                       float* __restrict__ bkdot){
  int t = blockIdx.x*256 + threadIdx.x;       // 0..9215
  int h = t / ND, c = t % ND;
  const float* wka = Wa + 64;
  float acc = 0.f;
  #pragma unroll 8
  for (int d=0; d<64; ++d) acc += Wk[(h*64+d)*ND + c] * wka[d];
  uk[h*ND + c] = acc;
  if (blockIdx.x==0 && threadIdx.x < NH){
    int hh = threadIdx.x; float a = 0.f;
    for (int d=0; d<64; ++d) a += bk[hh*64+d]*wka[d];
    bkdot[hh] = a;
  }
}

// lk[b,h,j] = nv[b,j,:] . uk[h] + bkdot[h]
__global__ void lk_kernel(const float* __restrict__ nv, const float* __restrict__ uk,
                          const float* __restrict__ bkdot, float* __restrict__ lk){
  int bj = blockIdx.x;                 // 0..4095  (b*128 + j)
  int b = bj >> 7, j = bj & 127;
  __shared__ float sh[ND];
  const float* row = nv + (size_t)bj * ND;
  for (int c = threadIdx.x; c < ND; c += 256) sh[c] = row[c];
  __syncthreads();
  int wave = threadIdx.x >> 6, lane = threadIdx.x & 63;
  #pragma unroll
  for (int hh=0; hh<3; ++hh){
    int h = wave*3 + hh;
    float acc = 0.f;
    #pragma unroll
    for (int c = lane; c < ND; c += 64) acc += sh[c]*uk[h*ND + c];
    acc = waveReduceSum(acc);
    if (lane==0) lk[(b*NH + h)*NS + j] = acc + bkdot[h];
  }
}

// ei[b,h,s] = desc[b,s,h*64+ :64] . we_a
__global__ void ei_kernel(const float* __restrict__ desc, const float* __restrict__ Wa,
                          float* __restrict__ ei){
  int bs = blockIdx.x;                // 0..4063  (b*127 + s)
  int b = bs / SD, s = bs % SD;
  int wave = threadIdx.x >> 6, lane = threadIdx.x & 63;
  float wea = Wa[128 + lane];
  const float* row = desc + (size_t)bs * ND;
  #pragma unroll
  for (int hh=0; hh<3; ++hh){
    int h = wave + hh*4;
    float v = row[h*64 + lane] * wea;
    v = waveReduceSum(v);
    if (lane==0) ei[(b*NH + h)*NS + s] = v;
  }
}

// Per (b,h): two softmaxes (row0 and rows>=1), write full attn block, save weights
__global__ void softmax_attn(const float* __restrict__ lk, const float* __restrict__ ei,
                             float* __restrict__ w, float* __restrict__ attn_out){
  int bh = blockIdx.x;                // 0..383
  int b = bh / NH, h = bh % NH;
  __shared__ float s0[NS], s1[NS], w0[NS], w1[NS];
  int t = threadIdx.x;
  if (t < NS){
    float lkv = lk[bh*NS + t];
    float ehh = 0.f, eh6 = 0.f;
    if (t >= 1){
      ehh = ei[(b*NH + h)*NS + t-1];
      eh6 = ei[(b*NH + (h % 6))*NS + t-1];
    }
    s0[t] = lkv + eh6;
    s1[t] = lkv + (h >= 6 ? ehh : 0.f);
  }
  __syncthreads();
  int wave = t >> 6, lane = t & 63;
  if (wave < 2){
    float* s  = wave ? s1 : s0;
    float* wd = wave ? w1 : w0;
    float x0 = (lane >= 1) ? s[lane] : -3.0e38f;
    float x1 = s[lane + 64];
    float m = waveReduceMax(fmaxf(x0, x1));
    float e0 = (lane >= 1) ? expf(x0 - m) : 0.f;
    float e1 = expf(x1 - m);
    float sum = waveReduceSum(e0 + e1);
    float inv = 1.f / sum;
    wd[lane]      = e0 * inv;   // lane0 -> exactly 0 (masked col 0)
    wd[lane + 64] = e1 * inv;
  }
  __syncthreads();
  if (t < NS){
    w[(bh*2 + 0)*NS + t] = w0[t];
    w[(bh*2 + 1)*NS + t] = w1[t];
  }
  // write attn block: row 0 = w0, rows 1..127 = w1  (128 rows x 32 float4)
  float4* out = (float4*)(attn_out + (size_t)bh * (NS*NS));
  for (int idx = t; idx < NS*32; idx += 256){
    int i = idx >> 5, q = idx & 31;
    const float* wsel = (i == 0) ? w0 : w1;
    float4 vv = { wsel[q*4], wsel[q*4+1], wsel[q*4+2], wsel[q*4+3] };
    out[i*32 + q] = vv;
  }
}

// Per (b,h,which): m[c] = sum_j w[j]*nv[b,j,c]; ctx[d] = m . Wv[h*64+d,:] + bv
__global__ void ctx_kernel(const float* __restrict__ nv, const float* __restrict__ Wv,
                           const float* __restrict__ bv, const float* __restrict__ w,
                           float* __restrict__ ctx){
  int blk = blockIdx.x;               // 0..767
  int b = blk / 24, r = blk % 24;
  int h = r >> 1, which = r & 1;
  __shared__ float wr[NS];
  __shared__ float m[ND];
  int t = threadIdx.x;
  if (t < NS) wr[t] = w[((b*NH + h)*2 + which)*NS + t];
  __syncthreads();
  float a0=0.f, a1=0.f, a2=0.f;
  const float* nvb = nv + (size_t)b * NS * ND;
  for (int j=1; j<NS; ++j){
    float wj = wr[j];
    const float* row = nvb + j*ND;
    a0 += wj*row[t];
    a1 += wj*row[t+256];
    a2 += wj*row[t+512];
  }
  m[t] = a0; m[t+256] = a1; m[t+512] = a2;
  __syncthreads();
  int wave = t >> 6, lane = t & 63;
  for (int dd=0; dd<16; ++dd){
    int d = wave*16 + dd;
    int rowi = h*64 + d;
    const float* wvrow = Wv + (size_t)rowi * ND;
    float acc = 0.f;
    #pragma unroll
    for (int k=0; k<12; ++k) acc += m[lane + 64*k] * wvrow[lane + 64*k];
    acc = waveReduceSum(acc);
    if (lane==0) ctx[((b*NH + h)*2 + which)*HD + d] = acc + bv[rowi];
  }
}

// basis_outputs[b,i,h,d] = ctx[b,h,(i!=0),d]  -- float4 vectorized
__global__ void basis_kernel(const float* __restrict__ ctx, float* __restrict__ out){
  int q = blockIdx.x*256 + threadIdx.x;      // float4 index, total 786432
  int dq = q & 15;
  int h  = (q >> 4) % NH;
  int i  = (q / 192) & 127;
  int b  = q / 24576;
  const float4* c4 = (const float4*)ctx;
  float4 v = c4[((b*NH + h)*2 + (i != 0))*16 + dq];
  ((float4*)out)[q] = v;
}

extern "C" void kernel_launch(void* const* d_in, const int* in_sizes, int n_in,
                              void* d_out, int out_size, void* d_ws, size_t ws_size,
                              hipStream_t stream) {
  const float* desc = (const float*)d_in[0];
  const float* nv   = (const float*)d_in[1];
  // d_in[2] = Wq, d_in[3] = bq : provably unused (softmax shift-invariance)
  const float* Wk   = (const float*)d_in[4];
  const float* bk   = (const float*)d_in[5];
  const float* Wv   = (const float*)d_in[6];
  const float* bv   = (const float*)d_in[7];
  const float* Wa   = (const float*)d_in[8];
  // d_in[9] = ba : unused (constant shift)
  float* out = (float*)d_out;
  float* ws  = (float*)d_ws;

  float* uk    = ws;             // 12*768   = 9216
  float* bkdot = ws + 9216;      // 16
  float* ei    = ws + 9232;      // 32*12*128 = 49152
  float* lkbuf = ws + 58384;     // 49152
  float* wbuf  = ws + 107536;    // 32*12*2*128 = 98304
  float* ctx   = ws + 205840;    // 32*12*2*64  = 49152
  float* attn_out = out + (size_t)NB*NS*ND;   // 3,145,728 offset

  fold_k      <<<36,   256, 0, stream>>>(Wk, bk, Wa, uk, bkdot);
  lk_kernel   <<<NB*NS,256, 0, stream>>>(nv, uk, bkdot, lkbuf);
  ei_kernel   <<<NB*SD,256, 0, stream>>>(desc, Wa, ei);
  softmax_attn<<<NB*NH,256, 0, stream>>>(lkbuf, ei, wbuf, attn_out);
  ctx_kernel  <<<NB*NH*2,256,0, stream>>>(nv, Wv, bv, wbuf, ctx);
  basis_kernel<<<3072, 256, 0, stream>>>(ctx, out);
}